// Round 1
// baseline (523.597 us; speedup 1.0000x reference)
//
#include <hip/hip_runtime.h>

typedef unsigned short u16;
typedef unsigned int   u32;
typedef short bf16x8 __attribute__((ext_vector_type(8)));
typedef float f32x16 __attribute__((ext_vector_type(16)));

#define NB    8
#define NP    3136
#define DIM   256
#define NQKV  768
#define PTILE 16
#define MROWS 64
#define NEGM  (-100.0f)
#define QKSCALE 0.17677669529663687f

// LDS layout (byte offsets). Phase 1: A_hi @0 (32K), A_lo @32768 (32K).
// Phase 2 (attention): Qatt @0 (512 rows * 33 bf16 = 33792B),
//                      Katt @33792, Vatt @67584 (512 rows * 33 f32 = 67584B).
// Phase 3: attnout hi @0 / lo @32768 (overwrites Q/K after dots barrier).
#define LDS_ALO 32768
#define LDS_K   33792
#define LDS_V   67584
#define LDS_SZ  135168

__device__ __constant__ float MASKS[2][4][4] = {
  {{0.f,0.f,0.f,NEGM},{0.f,0.f,NEGM,0.f},{0.f,NEGM,0.f,0.f},{NEGM,0.f,0.f,0.f}},
  {{0.f,NEGM,0.f,NEGM},{NEGM,0.f,NEGM,0.f},{NEGM,NEGM,NEGM,NEGM},{NEGM,NEGM,NEGM,NEGM}}
};

__device__ __forceinline__ u16 f2bf(float v) {
  u32 u = __float_as_uint(v);
  u = (u + 0x7FFFu + ((u >> 16) & 1u)) >> 16;
  return (u16)u;
}
__device__ __forceinline__ float bf2f(u16 h) {
  return __uint_as_float(((u32)h) << 16);
}

// ---------------- global-token means (deterministic 2-pass) ----------------
__global__ void mean_partial(const float* __restrict__ x,
                             const float* __restrict__ y,
                             float* __restrict__ part) {
  // grid: (32 chunks, 16 = arr*8+b), block 256 (= dims)
  const int chunk = blockIdx.x;
  const int ab = blockIdx.y;
  const int arr = ab >> 3, b = ab & 7;
  const float* src = arr ? y : x;
  const int d = threadIdx.x;
  float s = 0.f;
  const int p0 = chunk * 98;  // 3136 = 32*98
  for (int i = 0; i < 98; i++)
    s += src[((size_t)b * NP + p0 + i) * DIM + d];
  part[((size_t)ab * 32 + chunk) * DIM + d] = s;
}

__global__ void mean_final(const float* __restrict__ part, float* __restrict__ g) {
  const int ab = blockIdx.x;  // 0..15
  const int d = threadIdx.x;
  float s = 0.f;
  for (int c = 0; c < 32; c++) s += part[((size_t)ab * 32 + c) * DIM + d];
  g[ab * DIM + d] = s * (1.0f / 3136.0f);
}

// ---------------- W -> packed hi/lo bf16 fragments ----------------
// Consumption: for (ntile, kstep): lane holds B[n = nt*32+(lane&31)][k = ks*16+(lane>>5)*8 + j]
__global__ void pack_w(const float* __restrict__ W, u16* __restrict__ hi, u16* __restrict__ lo) {
  const int nt = blockIdx.x, ks = blockIdx.y, lane = threadIdx.x;
  const int n  = nt * 32 + (lane & 31);
  const int k0 = ks * 16 + ((lane >> 5) << 3);
  const float* src = W + (size_t)n * 256 + k0;
  const size_t o = (((size_t)nt * 16 + ks) * 64 + lane) * 8;
#pragma unroll
  for (int j = 0; j < 8; j++) {
    float v = src[j];
    u16 h = f2bf(v);
    hi[o + j] = h;
    lo[o + j] = f2bf(v - bf2f(h));
  }
}

// ---------------- fused stage kernel ----------------
template<int STAGE>
__global__ __launch_bounds__(512, 2)
void stage_kernel(const float* __restrict__ x, const float* __restrict__ y,
                  const float* __restrict__ g, const float* __restrict__ zin,
                  float* __restrict__ outp,
                  const u16* __restrict__ wq_hi, const u16* __restrict__ wq_lo,
                  const u16* __restrict__ wo_hi, const u16* __restrict__ wo_lo,
                  const float* __restrict__ bout) {
  extern __shared__ char lds[];
  const int tid  = threadIdx.x;
  const int lane = tid & 63;
  const int wave = tid >> 6;   // 0..7
  const int b    = blockIdx.y;
  const int pos0 = blockIdx.x * PTILE;

  // ---- stage Z tile (64 rows x 256) into A_hi/A_lo, XOR-swizzled ----
  {
    const int r   = tid >> 3;          // 0..63
    const int cb  = (tid & 7) * 32;
    const int pos = pos0 + (r >> 2);
    const int tok = r & 3;
    const float* src;
    if (STAGE == 0) {
      if (tok == 0)      src = x + ((size_t)b * NP + pos) * DIM;
      else if (tok == 1) src = y + ((size_t)b * NP + pos) * DIM;
      else if (tok == 2) src = g + b * DIM;
      else               src = g + (8 + b) * DIM;
    } else {
      src = zin + (((size_t)b * NP + pos) * 4 + tok) * DIM;
    }
#pragma unroll
    for (int u = 0; u < 8; u++) {
      const int col = cb + u * 4;
      float4 v = *(const float4*)(src + col);
      u16 h0 = f2bf(v.x), h1 = f2bf(v.y), h2 = f2bf(v.z), h3 = f2bf(v.w);
      u16 l0 = f2bf(v.x - bf2f(h0)), l1 = f2bf(v.y - bf2f(h1));
      u16 l2 = f2bf(v.z - bf2f(h2)), l3 = f2bf(v.w - bf2f(h3));
      uint2 hw, lw;
      hw.x = (u32)h0 | ((u32)h1 << 16); hw.y = (u32)h2 | ((u32)h3 << 16);
      lw.x = (u32)l0 | ((u32)l1 << 16); lw.y = (u32)l2 | ((u32)l3 << 16);
      const int bo = (r * 512 + col * 2) ^ ((r & 7) << 4);
      *(uint2*)(lds + bo)           = hw;
      *(uint2*)(lds + LDS_ALO + bo) = lw;
    }
  }
  __syncthreads();

  // ---- GEMM1: QKV(64x768) = Z @ Wqkv^T, split-bf16 3-pass ----
  f32x16 acc[2][3];
#pragma unroll
  for (int m = 0; m < 2; m++)
#pragma unroll
    for (int t = 0; t < 3; t++)
#pragma unroll
      for (int i = 0; i < 16; i++) acc[m][t][i] = 0.f;

  const int nt0  = wave * 3;            // n-tiles owned: nt0..nt0+2
  const int arow = lane & 31;
  const int kgrp = (lane >> 5) << 3;
  for (int ks = 0; ks < 16; ks++) {
    bf16x8 ahi[2], alo[2];
#pragma unroll
    for (int m = 0; m < 2; m++) {
      const int r  = m * 32 + arow;
      const int bo = (r * 512 + (ks * 16 + kgrp) * 2) ^ ((r & 7) << 4);
      ahi[m] = *(const bf16x8*)(lds + bo);
      alo[m] = *(const bf16x8*)(lds + LDS_ALO + bo);
    }
#pragma unroll
    for (int t = 0; t < 3; t++) {
      const size_t o = (((size_t)(nt0 + t) * 16 + ks) * 64 + lane) * 8;
      bf16x8 bhi = *(const bf16x8*)(wq_hi + o);
      bf16x8 blo = *(const bf16x8*)(wq_lo + o);
#pragma unroll
      for (int m = 0; m < 2; m++) {
        acc[m][t] = __builtin_amdgcn_mfma_f32_32x32x16_bf16(ahi[m], bhi, acc[m][t], 0, 0, 0);
        acc[m][t] = __builtin_amdgcn_mfma_f32_32x32x16_bf16(ahi[m], blo, acc[m][t], 0, 0, 0);
        acc[m][t] = __builtin_amdgcn_mfma_f32_32x32x16_bf16(alo[m], bhi, acc[m][t], 0, 0, 0);
      }
    }
  }
  __syncthreads();  // A region dead; safe to overwrite with Q/K/V

  // ---- scatter acc -> Qatt(bf16)/Katt(bf16)/Vatt(f32), stride-33 padded ----
  {
    const int cl = lane & 31;
    const int rh = (lane >> 5) << 2;
#pragma unroll
    for (int m = 0; m < 2; m++)
#pragma unroll
      for (int t = 0; t < 3; t++) {
        const int c    = (nt0 + t) * 32 + cl;
        const int head = (c >> 5) & 7;
        const int d    = c & 31;
        const int sel  = c >> 8;  // 0=Q 1=K 2=V
#pragma unroll
        for (int i = 0; i < 16; i++) {
          const int r      = m * 32 + (i & 3) + ((i >> 2) << 3) + rh;
          const int rowidx = ((r >> 2) * 8 + head) * 4 + (r & 3);
          const float v    = acc[m][t][i];
          if (sel == 0)      *(u16*)(lds + rowidx * 66 + d * 2)           = f2bf(v);
          else if (sel == 1) *(u16*)(lds + LDS_K + rowidx * 66 + d * 2)   = f2bf(v);
          else               *(float*)(lds + LDS_V + rowidx * 132 + d * 4) = v;
        }
      }
  }
  __syncthreads();

  // ---- attention: one (pos, head, row) per thread ----
  float p0, p1, p2, p3;
  const int apos  = tid >> 5;
  const int ahead = (tid >> 2) & 7;
  const int arowt = tid & 3;
  const int abase = (apos * 8 + ahead) * 4;
  {
    float q[32];
    const char* qptr = lds + (abase + arowt) * 66;
#pragma unroll
    for (int d = 0; d < 32; d++) q[d] = bf2f(*(const u16*)(qptr + d * 2));
    float dots[4];
#pragma unroll
    for (int j = 0; j < 4; j++) {
      const char* kptr = lds + LDS_K + (abase + j) * 66;
      float s = 0.f;
#pragma unroll
      for (int d = 0; d < 32; d++) s += q[d] * bf2f(*(const u16*)(kptr + d * 2));
      dots[j] = s * QKSCALE + MASKS[STAGE][arowt][j];
    }
    float mx = fmaxf(fmaxf(dots[0], dots[1]), fmaxf(dots[2], dots[3]));
    float e0 = __expf(dots[0] - mx), e1 = __expf(dots[1] - mx);
    float e2 = __expf(dots[2] - mx), e3 = __expf(dots[3] - mx);
    float inv = 1.f / (e0 + e1 + e2 + e3);
    p0 = e0 * inv; p1 = e1 * inv; p2 = e2 * inv; p3 = e3 * inv;
  }
  __syncthreads();  // all dots read Q/K; region now reusable for attnout

  {
    const float* v0 = (const float*)(lds + LDS_V + (size_t)(abase + 0) * 132);
    const float* v1 = (const float*)(lds + LDS_V + (size_t)(abase + 1) * 132);
    const float* v2 = (const float*)(lds + LDS_V + (size_t)(abase + 2) * 132);
    const float* v3 = (const float*)(lds + LDS_V + (size_t)(abase + 3) * 132);
    const int R  = apos * 4 + arowt;
    const int sw = (R & 7) << 4;
#pragma unroll
    for (int d = 0; d < 32; d += 2) {
      float o0 = p0 * v0[d]     + p1 * v1[d]     + p2 * v2[d]     + p3 * v3[d];
      float o1 = p0 * v0[d + 1] + p1 * v1[d + 1] + p2 * v2[d + 1] + p3 * v3[d + 1];
      u16 h0 = f2bf(o0), h1 = f2bf(o1);
      u16 g0 = f2bf(o0 - bf2f(h0)), g1 = f2bf(o1 - bf2f(h1));
      const int col = ahead * 32 + d;
      const int bo  = (R * 512 + col * 2) ^ sw;
      *(u32*)(lds + bo)           = (u32)h0 | ((u32)h1 << 16);
      *(u32*)(lds + LDS_ALO + bo) = (u32)g0 | ((u32)g1 << 16);
    }
  }
  __syncthreads();

  // ---- GEMM2: out(64x256) = attnout @ Wout^T ----
  f32x16 acc2[2];
#pragma unroll
  for (int m = 0; m < 2; m++)
#pragma unroll
    for (int i = 0; i < 16; i++) acc2[m][i] = 0.f;

  const int ntw = wave;  // 0..7 n-tiles
  for (int ks = 0; ks < 16; ks++) {
    bf16x8 ahi[2], alo[2];
#pragma unroll
    for (int m = 0; m < 2; m++) {
      const int r  = m * 32 + arow;
      const int bo = (r * 512 + (ks * 16 + kgrp) * 2) ^ ((r & 7) << 4);
      ahi[m] = *(const bf16x8*)(lds + bo);
      alo[m] = *(const bf16x8*)(lds + LDS_ALO + bo);
    }
    const size_t o = (((size_t)ntw * 16 + ks) * 64 + lane) * 8;
    bf16x8 bhi = *(const bf16x8*)(wo_hi + o);
    bf16x8 blo = *(const bf16x8*)(wo_lo + o);
#pragma unroll
    for (int m = 0; m < 2; m++) {
      acc2[m] = __builtin_amdgcn_mfma_f32_32x32x16_bf16(ahi[m], bhi, acc2[m], 0, 0, 0);
      acc2[m] = __builtin_amdgcn_mfma_f32_32x32x16_bf16(ahi[m], blo, acc2[m], 0, 0, 0);
      acc2[m] = __builtin_amdgcn_mfma_f32_32x32x16_bf16(alo[m], bhi, acc2[m], 0, 0, 0);
    }
  }

  // ---- epilogue: + bias, write out ----
  const int c = ntw * 32 + (lane & 31);
  const float bc = bout[c];
  const size_t TOT = (size_t)NB * NP * DIM;
#pragma unroll
  for (int m = 0; m < 2; m++)
#pragma unroll
    for (int i = 0; i < 16; i++) {
      const int r   = m * 32 + (i & 3) + ((i >> 2) << 3) + ((lane >> 5) << 2);
      const int pos = pos0 + (r >> 2);
      const int tok = r & 3;
      const float v = acc2[m][i] + bc;
      if (STAGE == 0) {
        outp[(((size_t)b * NP + pos) * 4 + tok) * DIM + c] = v;
      } else {
        if (tok == 0)      outp[((size_t)b * NP + pos) * DIM + c] = v;
        else if (tok == 1) outp[TOT + ((size_t)b * NP + pos) * DIM + c] = v;
      }
    }
}

extern "C" void kernel_launch(void* const* d_in, const int* in_sizes, int n_in,
                              void* d_out, int out_size, void* d_ws, size_t ws_size,
                              hipStream_t stream) {
  const float* x     = (const float*)d_in[0];
  const float* y     = (const float*)d_in[1];
  const float* wqkv0 = (const float*)d_in[2];
  const float* wout0 = (const float*)d_in[3];
  const float* bout0 = (const float*)d_in[4];
  const float* wqkv1 = (const float*)d_in[5];
  const float* wout1 = (const float*)d_in[6];
  const float* bout1 = (const float*)d_in[7];

  float* zmid = (float*)d_ws;                        // 8*3136*4*256 f32 = 102.8 MB
  float* part = zmid + (size_t)NB * NP * 4 * DIM;    // 16*32*256 f32
  float* g    = part + (size_t)16 * 32 * DIM;        // 16*256 f32
  u16* w = (u16*)(g + 16 * DIM);
  u16* wq0_hi = w; w += 768 * 256;
  u16* wq0_lo = w; w += 768 * 256;
  u16* wo0_hi = w; w += 256 * 256;
  u16* wo0_lo = w; w += 256 * 256;
  u16* wq1_hi = w; w += 768 * 256;
  u16* wq1_lo = w; w += 768 * 256;
  u16* wo1_hi = w; w += 256 * 256;
  u16* wo1_lo = w; w += 256 * 256;

  mean_partial<<<dim3(32, 16), dim3(256), 0, stream>>>(x, y, part);
  mean_final<<<dim3(16), dim3(256), 0, stream>>>(part, g);

  pack_w<<<dim3(24, 16), dim3(64), 0, stream>>>(wqkv0, wq0_hi, wq0_lo);
  pack_w<<<dim3(8, 16),  dim3(64), 0, stream>>>(wout0, wo0_hi, wo0_lo);
  pack_w<<<dim3(24, 16), dim3(64), 0, stream>>>(wqkv1, wq1_hi, wq1_lo);
  pack_w<<<dim3(8, 16),  dim3(64), 0, stream>>>(wout1, wo1_hi, wo1_lo);

  stage_kernel<0><<<dim3(NP / PTILE, NB), dim3(512), LDS_SZ, stream>>>(
      x, y, g, nullptr, zmid, wq0_hi, wq0_lo, wo0_hi, wo0_lo, bout0);
  stage_kernel<1><<<dim3(NP / PTILE, NB), dim3(512), LDS_SZ, stream>>>(
      nullptr, nullptr, nullptr, zmid, (float*)d_out,
      wq1_hi, wq1_lo, wo1_hi, wo1_lo, bout1);
}

// Round 2
// 419.692 us; speedup vs baseline: 1.2476x; 1.2476x over previous
//
#include <hip/hip_runtime.h>

typedef unsigned short u16;
typedef unsigned int   u32;
typedef short bf16x8 __attribute__((ext_vector_type(8)));
typedef float f32x16 __attribute__((ext_vector_type(16)));

#define NB    8
#define NP    3136
#define DIM   256
#define PTILE 8
#define NEGM  (-100.0f)
#define QKSCALE 0.17677669529663687f

// LDS layout (byte offsets), region reused across barrier-separated phases:
// Phase 1 (GEMM1 A):   A_hi @0 (16K), A_lo @16384 (16K)
// Phase 2 (attention): Q bf16 @0 (256 rows * 66B = 16896),
//                      K bf16 @16896, V f32 @33792 (256 rows * 132B = 33792)
// Phase 3 (GEMM2 A):   AO_hi @0 (16K), AO_lo @16384 (overwrites Q/K; V-read disjoint)
#define LDS_ALO 16384
#define LDS_K   16896
#define LDS_V   33792
#define LDS_SZ  67584

__device__ __constant__ float MASKS[2][4][4] = {
  {{0.f,0.f,0.f,NEGM},{0.f,0.f,NEGM,0.f},{0.f,NEGM,0.f,0.f},{NEGM,0.f,0.f,0.f}},
  {{0.f,NEGM,0.f,NEGM},{NEGM,0.f,NEGM,0.f},{NEGM,NEGM,NEGM,NEGM},{NEGM,NEGM,NEGM,NEGM}}
};

__device__ __forceinline__ u16 f2bf(float v) {
  u32 u = __float_as_uint(v);
  u = (u + 0x7FFFu + ((u >> 16) & 1u)) >> 16;
  return (u16)u;
}
__device__ __forceinline__ float bf2f(u16 h) {
  return __uint_as_float(((u32)h) << 16);
}

// ---------------- global-token means (deterministic 2-pass) ----------------
__global__ void mean_partial(const float* __restrict__ x,
                             const float* __restrict__ y,
                             float* __restrict__ part) {
  const int chunk = blockIdx.x;
  const int ab = blockIdx.y;
  const int b = ab & 7;
  const float* src = (ab >> 3) ? y : x;
  const int d = threadIdx.x;
  float s = 0.f;
  const int p0 = chunk * 98;  // 3136 = 32*98
  for (int i = 0; i < 98; i++)
    s += src[((size_t)b * NP + p0 + i) * DIM + d];
  part[((size_t)ab * 32 + chunk) * DIM + d] = s;
}

__global__ void mean_final(const float* __restrict__ part, float* __restrict__ g) {
  const int ab = blockIdx.x;
  const int d = threadIdx.x;
  float s = 0.f;
  for (int c = 0; c < 32; c++) s += part[((size_t)ab * 32 + c) * DIM + d];
  g[ab * DIM + d] = s * (1.0f / 3136.0f);
}

// ---------------- W -> packed hi/lo bf16 fragments ----------------
__global__ void pack_w(const float* __restrict__ W, u16* __restrict__ hi, u16* __restrict__ lo) {
  const int nt = blockIdx.x, ks = blockIdx.y, lane = threadIdx.x;
  const int n  = nt * 32 + (lane & 31);
  const int k0 = ks * 16 + ((lane >> 5) << 3);
  const float* src = W + (size_t)n * 256 + k0;
  const size_t o = (((size_t)nt * 16 + ks) * 64 + lane) * 8;
#pragma unroll
  for (int j = 0; j < 8; j++) {
    float v = src[j];
    u16 h = f2bf(v);
    hi[o + j] = h;
    lo[o + j] = f2bf(v - bf2f(h));
  }
}

// ---------------- fused stage kernel ----------------
template<int STAGE>
__global__ __launch_bounds__(512, 4)
void stage_kernel(const float* __restrict__ x, const float* __restrict__ y,
                  const float* __restrict__ g, const float* __restrict__ zin,
                  float* __restrict__ outp,
                  const u16* __restrict__ wq_hi, const u16* __restrict__ wq_lo,
                  const u16* __restrict__ wo_hi, const u16* __restrict__ wo_lo,
                  const float* __restrict__ bout) {
  extern __shared__ char lds[];
  const int tid  = threadIdx.x;
  const int lane = tid & 63;
  const int wave = tid >> 6;   // 0..7
  const int b    = blockIdx.y;
  const int pos0 = blockIdx.x * PTILE;

  // ---- stage Z tile (32 rows x 256) into A_hi/A_lo, 16-row XOR swizzle ----
  {
    const int r   = tid >> 4;          // 0..31
    const int cb  = (tid & 15) * 16;
    const int pos = pos0 + (r >> 2);
    const int tok = r & 3;
    const float* src;
    if (STAGE == 0) {
      if (tok == 0)      src = x + ((size_t)b * NP + pos) * DIM;
      else if (tok == 1) src = y + ((size_t)b * NP + pos) * DIM;
      else if (tok == 2) src = g + b * DIM;
      else               src = g + (8 + b) * DIM;
    } else {
      src = zin + (((size_t)b * NP + pos) * 4 + tok) * DIM;
    }
    const int sw = (r & 15) << 4;
#pragma unroll
    for (int u = 0; u < 4; u++) {
      const int col = cb + u * 4;
      float4 v = *(const float4*)(src + col);
      u16 h0 = f2bf(v.x), h1 = f2bf(v.y), h2 = f2bf(v.z), h3 = f2bf(v.w);
      u16 l0 = f2bf(v.x - bf2f(h0)), l1 = f2bf(v.y - bf2f(h1));
      u16 l2 = f2bf(v.z - bf2f(h2)), l3 = f2bf(v.w - bf2f(h3));
      uint2 hw, lw;
      hw.x = (u32)h0 | ((u32)h1 << 16); hw.y = (u32)h2 | ((u32)h3 << 16);
      lw.x = (u32)l0 | ((u32)l1 << 16); lw.y = (u32)l2 | ((u32)l3 << 16);
      const int bo = (r * 512 + col * 2) ^ sw;
      *(uint2*)(lds + bo)           = hw;
      *(uint2*)(lds + LDS_ALO + bo) = lw;
    }
  }
  __syncthreads();

  // ---- GEMM1: QKV(32x768) = Z @ Wqkv^T, split-bf16 3-pass ----
  f32x16 acc[3];
#pragma unroll
  for (int t = 0; t < 3; t++)
#pragma unroll
    for (int i = 0; i < 16; i++) acc[t][i] = 0.f;

  const int nt0  = wave * 3;
  const int arow = lane & 31;
  const int kgrp = (lane >> 5) << 3;
  for (int ks = 0; ks < 16; ks++) {
    const int bo = (arow * 512 + (ks * 16 + kgrp) * 2) ^ ((arow & 15) << 4);
    bf16x8 ahi = *(const bf16x8*)(lds + bo);
    bf16x8 alo = *(const bf16x8*)(lds + LDS_ALO + bo);
#pragma unroll
    for (int t = 0; t < 3; t++) {
      const size_t o = (((size_t)(nt0 + t) * 16 + ks) * 64 + lane) * 8;
      bf16x8 bhi = *(const bf16x8*)(wq_hi + o);
      bf16x8 blo = *(const bf16x8*)(wq_lo + o);
      __builtin_amdgcn_s_setprio(1);
      acc[t] = __builtin_amdgcn_mfma_f32_32x32x16_bf16(ahi, bhi, acc[t], 0, 0, 0);
      acc[t] = __builtin_amdgcn_mfma_f32_32x32x16_bf16(ahi, blo, acc[t], 0, 0, 0);
      acc[t] = __builtin_amdgcn_mfma_f32_32x32x16_bf16(alo, bhi, acc[t], 0, 0, 0);
      __builtin_amdgcn_s_setprio(0);
    }
  }
  __syncthreads();  // A region dead; safe to overwrite with Q/K/V

  // ---- scatter acc -> Q(bf16)/K(bf16)/V(f32), stride-33 padded ----
  {
    const int cl = lane & 31;
    const int rh = (lane >> 5) << 2;
#pragma unroll
    for (int t = 0; t < 3; t++) {
      const int c    = (nt0 + t) * 32 + cl;
      const int head = (c >> 5) & 7;
      const int d    = c & 31;
      const int sel  = c >> 8;  // 0=Q 1=K 2=V
#pragma unroll
      for (int i = 0; i < 16; i++) {
        const int r      = (i & 3) + ((i >> 2) << 3) + rh;   // 0..31
        const int rowidx = ((r >> 2) * 8 + head) * 4 + (r & 3);
        const float v    = acc[t][i];
        if (sel == 0)      *(u16*)(lds + rowidx * 66 + d * 2)            = f2bf(v);
        else if (sel == 1) *(u16*)(lds + LDS_K + rowidx * 66 + d * 2)    = f2bf(v);
        else               *(float*)(lds + LDS_V + rowidx * 132 + d * 4) = v;
      }
    }
  }
  __syncthreads();

  // ---- attention: item=(pos,head,row) split across thread pairs over d ----
  float p0, p1, p2, p3;
  const int item  = tid >> 1;          // 0..255
  const int half  = tid & 1;
  const int apos  = item >> 5;         // 0..7
  const int ahead = (item >> 2) & 7;
  const int arowt = item & 3;
  const int abase = (apos * 8 + ahead) * 4;
  const int d0    = half * 16;
  {
    float q[16];
    const char* qptr = lds + (abase + arowt) * 66 + d0 * 2;
#pragma unroll
    for (int dd = 0; dd < 16; dd++) q[dd] = bf2f(*(const u16*)(qptr + dd * 2));
    float dots[4];
#pragma unroll
    for (int j = 0; j < 4; j++) {
      const char* kptr = lds + LDS_K + (abase + j) * 66 + d0 * 2;
      float s = 0.f;
#pragma unroll
      for (int dd = 0; dd < 16; dd++) s += q[dd] * bf2f(*(const u16*)(kptr + dd * 2));
      dots[j] = s;
    }
#pragma unroll
    for (int j = 0; j < 4; j++) {
      dots[j] += __shfl_xor(dots[j], 1);
      dots[j] = dots[j] * QKSCALE + MASKS[STAGE][arowt][j];
    }
    float mx = fmaxf(fmaxf(dots[0], dots[1]), fmaxf(dots[2], dots[3]));
    float e0 = __expf(dots[0] - mx), e1 = __expf(dots[1] - mx);
    float e2 = __expf(dots[2] - mx), e3 = __expf(dots[3] - mx);
    float inv = 1.f / (e0 + e1 + e2 + e3);
    p0 = e0 * inv; p1 = e1 * inv; p2 = e2 * inv; p3 = e3 * inv;
  }
  __syncthreads();  // Q/K region now reusable for attnout; V still live (disjoint)

  // ---- PV (thread's 16 d's) + write attnout hi/lo ----
  {
    const float* v0 = (const float*)(lds + LDS_V + (size_t)(abase + 0) * 132) + d0;
    const float* v1 = (const float*)(lds + LDS_V + (size_t)(abase + 1) * 132) + d0;
    const float* v2 = (const float*)(lds + LDS_V + (size_t)(abase + 2) * 132) + d0;
    const float* v3 = (const float*)(lds + LDS_V + (size_t)(abase + 3) * 132) + d0;
    const int R  = apos * 4 + arowt;   // 0..31
    const int sw = (R & 15) << 4;
#pragma unroll
    for (int dd = 0; dd < 16; dd += 2) {
      float o0 = p0 * v0[dd]     + p1 * v1[dd]     + p2 * v2[dd]     + p3 * v3[dd];
      float o1 = p0 * v0[dd + 1] + p1 * v1[dd + 1] + p2 * v2[dd + 1] + p3 * v3[dd + 1];
      u16 h0 = f2bf(o0), h1 = f2bf(o1);
      u16 g0 = f2bf(o0 - bf2f(h0)), g1 = f2bf(o1 - bf2f(h1));
      const int col = ahead * 32 + d0 + dd;
      const int bo  = (R * 512 + col * 2) ^ sw;
      *(u32*)(lds + bo)           = (u32)h0 | ((u32)h1 << 16);
      *(u32*)(lds + LDS_ALO + bo) = (u32)g0 | ((u32)g1 << 16);
    }
  }
  __syncthreads();

  // ---- GEMM2: out(32x256) = attnout @ Wout^T ----
  f32x16 acc2;
#pragma unroll
  for (int i = 0; i < 16; i++) acc2[i] = 0.f;

  const int ntw = wave;  // 0..7
  for (int ks = 0; ks < 16; ks++) {
    const int bo = (arow * 512 + (ks * 16 + kgrp) * 2) ^ ((arow & 15) << 4);
    bf16x8 ahi = *(const bf16x8*)(lds + bo);
    bf16x8 alo = *(const bf16x8*)(lds + LDS_ALO + bo);
    const size_t o = (((size_t)ntw * 16 + ks) * 64 + lane) * 8;
    bf16x8 bhi = *(const bf16x8*)(wo_hi + o);
    bf16x8 blo = *(const bf16x8*)(wo_lo + o);
    __builtin_amdgcn_s_setprio(1);
    acc2 = __builtin_amdgcn_mfma_f32_32x32x16_bf16(ahi, bhi, acc2, 0, 0, 0);
    acc2 = __builtin_amdgcn_mfma_f32_32x32x16_bf16(ahi, blo, acc2, 0, 0, 0);
    acc2 = __builtin_amdgcn_mfma_f32_32x32x16_bf16(alo, bhi, acc2, 0, 0, 0);
    __builtin_amdgcn_s_setprio(0);
  }

  // ---- epilogue: + bias, write out ----
  const int c = ntw * 32 + (lane & 31);
  const float bc = bout[c];
  const size_t TOT = (size_t)NB * NP * DIM;
#pragma unroll
  for (int i = 0; i < 16; i++) {
    const int r   = (i & 3) + ((i >> 2) << 3) + ((lane >> 5) << 2);
    const int pos = pos0 + (r >> 2);
    const int tok = r & 3;
    const float v = acc2[i] + bc;
    if (STAGE == 0) {
      outp[(((size_t)b * NP + pos) * 4 + tok) * DIM + c] = v;
    } else {
      if (tok == 0)      outp[((size_t)b * NP + pos) * DIM + c] = v;
      else if (tok == 1) outp[TOT + ((size_t)b * NP + pos) * DIM + c] = v;
    }
  }
}

extern "C" void kernel_launch(void* const* d_in, const int* in_sizes, int n_in,
                              void* d_out, int out_size, void* d_ws, size_t ws_size,
                              hipStream_t stream) {
  const float* x     = (const float*)d_in[0];
  const float* y     = (const float*)d_in[1];
  const float* wqkv0 = (const float*)d_in[2];
  const float* wout0 = (const float*)d_in[3];
  const float* bout0 = (const float*)d_in[4];
  const float* wqkv1 = (const float*)d_in[5];
  const float* wout1 = (const float*)d_in[6];
  const float* bout1 = (const float*)d_in[7];

  float* zmid = (float*)d_ws;                        // 8*3136*4*256 f32 = 102.8 MB
  float* part = zmid + (size_t)NB * NP * 4 * DIM;
  float* g    = part + (size_t)16 * 32 * DIM;
  u16* w = (u16*)(g + 16 * DIM);
  u16* wq0_hi = w; w += 768 * 256;
  u16* wq0_lo = w; w += 768 * 256;
  u16* wo0_hi = w; w += 256 * 256;
  u16* wo0_lo = w; w += 256 * 256;
  u16* wq1_hi = w; w += 768 * 256;
  u16* wq1_lo = w; w += 768 * 256;
  u16* wo1_hi = w; w += 256 * 256;
  u16* wo1_lo = w; w += 256 * 256;

  mean_partial<<<dim3(32, 16), dim3(256), 0, stream>>>(x, y, part);
  mean_final<<<dim3(16), dim3(256), 0, stream>>>(part, g);

  pack_w<<<dim3(24, 16), dim3(64), 0, stream>>>(wqkv0, wq0_hi, wq0_lo);
  pack_w<<<dim3(8, 16),  dim3(64), 0, stream>>>(wout0, wo0_hi, wo0_lo);
  pack_w<<<dim3(24, 16), dim3(64), 0, stream>>>(wqkv1, wq1_hi, wq1_lo);
  pack_w<<<dim3(8, 16),  dim3(64), 0, stream>>>(wout1, wo1_hi, wo1_lo);

  stage_kernel<0><<<dim3(NP / PTILE, NB), dim3(512), LDS_SZ, stream>>>(
      x, y, g, nullptr, zmid, wq0_hi, wq0_lo, wo0_hi, wo0_lo, bout0);
  stage_kernel<1><<<dim3(NP / PTILE, NB), dim3(512), LDS_SZ, stream>>>(
      nullptr, nullptr, nullptr, zmid, (float*)d_out,
      wq1_hi, wq1_lo, wo1_hi, wo1_lo, bout1);
}